// Round 9
// baseline (161.734 us; speedup 1.0000x reference)
//
#include <hip/hip_runtime.h>

// BackgroundNoiseLayer, round 9: fused kernel, write-pattern-centric geometry.
//   out[t, n*5+r] = sum_k spikes[t,k] * W[k, n*5+r],
//   W[k, c] = scatter-add over edges e (cols[e]=k, rows[e]=n) of weights[e]*tau[e,r]
//
// memset: zero bin counters
// K1 : bucket edges (bin = row/32, 16 B records {key, 5 bf16 w*tau});
//      also builds fragment-ordered bf16 spike table spbf[nt][kk][lane].
// K2 : per block (32 neurons = 160 cols = 5 FULL 128B lines per t-row):
//      preload records -> zero f32 LDS slice -> LDS atomic scatter ->
//      one bf16 convert into transposed (c&15)-swizzled LDS -> MFMA GEMM
//      with stores INTERLEAVED per t-tile-pair. 8 waves: 2 c-groups x 4
//      t-groups. Bijective XCD swizzle on bin ids for L2 write locality.

#define N_NEURONS 50000
#define N_BKG     100
#define N_SYN     5
#define N_EDGES   500000
#define SEQ_T     250
#define NCOL      (N_NEURONS * N_SYN)   // 250000
#define RPB       32                    // neurons per bin
#define NBINS     1563                  // ceil(50000/32)
#define CAP       768                   // record cap (mean 320, +25 sigma)
#define CPADF     161                   // f32 slice stride (100 x 161)
#define BCOLS     160                   // cols per bin = 5 full cache lines
#define NXCD      8

#define LDS_BYTES 64512                 // >= max(100*161*4=64400, 160*256=40960)

// d_ws layout
#define WS_COUNT_OFF 0                  // NBINS u32
#define WS_SPB_OFF   32768              // 4096 * 16 B = 64 KB spike frags
#define WS_REC_OFF   131072             // NBINS*CAP*16 B = 19.2 MB

typedef __attribute__((ext_vector_type(8))) short bf16x8;
typedef __attribute__((ext_vector_type(4))) float f32x4;

__device__ inline unsigned short bf16_rne(float f) {
    unsigned u = __builtin_bit_cast(unsigned, f);
    u += 0x7FFFu + ((u >> 16) & 1u);
    return (unsigned short)(u >> 16);
}
__device__ inline float bf16_up(unsigned hw) {
    return __builtin_bit_cast(float, hw << 16);
}

// K1: bucket-append edges; gids < 4096 also build the fragment-ordered
// spike table: unit gid = (nt*4 + kk)*64 + lane, value[i] =
// bf16(spikes[t, k0+i]), t = nt*16+(lane&15), k0 = kk*32+(lane>>4)*8.
__global__ __launch_bounds__(256) void bucket_kernel(
        const float* __restrict__ weights,
        const float* __restrict__ tau,
        const int*   __restrict__ rows,
        const int*   __restrict__ cols,
        const float* __restrict__ spikes,
        unsigned* __restrict__ count,
        uint4* __restrict__ rec,
        bf16x8* __restrict__ spbf) {
    int gid = blockIdx.x * 256 + threadIdx.x;
    if (gid < 4096) {
        int lane = gid & 63;
        int kk   = (gid >> 6) & 3;
        int nt   = gid >> 8;
        int t    = nt * 16 + (lane & 15);
        int k0   = kk * 32 + (lane >> 4) * 8;
        bf16x8 v;
#pragma unroll
        for (int i = 0; i < 8; ++i) {
            float s = 0.f;
            if (t < SEQ_T && (k0 + i) < N_BKG)
                s = spikes[t * N_BKG + k0 + i];      // 0/1 -> bf16 exact
            v[i] = (short)bf16_rne(s);
        }
        spbf[gid] = v;
    }
    if (gid >= N_EDGES) return;
    int row = rows[gid];
    int col = cols[gid];
    float w = weights[gid];
    const float* tp = tau + (size_t)gid * N_SYN;
    int bin = row >> 5;                          // row / RPB
    unsigned slot = atomicAdd(&count[bin], 1u);
    if (slot >= CAP) return;                     // statistically impossible
    uint4 r;
    r.x = ((unsigned)col << 5) | (unsigned)(row & 31);
    r.y = (unsigned)bf16_rne(w * tp[0]) | ((unsigned)bf16_rne(w * tp[1]) << 16);
    r.z = (unsigned)bf16_rne(w * tp[2]) | ((unsigned)bf16_rne(w * tp[3]) << 16);
    r.w = (unsigned)bf16_rne(w * tp[4]);
    rec[(size_t)bin * CAP + slot] = r;
}

// K2: fused scatter + convert + MFMA GEMM. NBINS blocks x 512 (8 waves).
// Wave wv: c-group cg = wv&1 (80 cols), t-group tg = wv>>1 (64 t-rows).
// Swapped operands: A = W bf16 frag (M = c), B = spike frag (N = t),
// k = (l>>4)*8 + i. D: col = t = l&15, row = c = (l>>4)*4+reg ->
// f32x4 stores along c (mapping verified rounds 5-8).
// bf16 LDS layout: byte = (c<<8) + (k<<1), swizzle XOR ((c&15)<<4):
// 16 consecutive c -> 16 distinct 16B slots (2-way on banks = free).
__global__ __launch_bounds__(512, 4) void fused_kernel(
        const unsigned* __restrict__ count,
        const uint4* __restrict__ rec,
        const bf16x8* __restrict__ spbf,
        float* __restrict__ out) {
    __shared__ __align__(16) char lds[LDS_BYTES];
    float* slice = (float*)lds;                  // f32 [100][161]

    const int tid = threadIdx.x;

    // bijective XCD swizzle (m204): contiguous bin chunk per XCD
    const int orig = blockIdx.x;
    const int xcd  = orig & (NXCD - 1);
    const int q    = NBINS >> 3;                 // 195
    const int r8   = NBINS & 7;                  // 3
    const int bin  = (xcd < r8 ? xcd * (q + 1)
                               : r8 * (q + 1) + (xcd - r8) * q) + (orig >> 3);

    // ---- preload this block's records (rec is sized NBINS*CAP; safe) ----
    unsigned cnt = count[bin];
    if (cnt > CAP) cnt = CAP;
    uint4 ra = rec[(size_t)bin * CAP + tid];
    uint4 rb;
    if (tid < 256) rb = rec[(size_t)bin * CAP + 512 + tid];

    // ---- zero entire LDS (covers f32 slice incl. pad) ----
    {
        f32x4* s4 = (f32x4*)lds;
        f32x4 z = (f32x4){0.f, 0.f, 0.f, 0.f};
#pragma unroll
        for (int j = 0; j < 8; ++j) {
            int i = tid + j * 512;
            if (i < LDS_BYTES / 16) s4[i] = z;
        }
    }
    __syncthreads();

    // ---- LDS f32 atomic scatter ----
    if ((unsigned)tid < cnt) {
        float* base = &slice[(ra.x >> 5) * CPADF + (ra.x & 31u) * N_SYN];
        atomicAdd(base + 0, bf16_up(ra.y & 0xFFFFu));
        atomicAdd(base + 1, bf16_up(ra.y >> 16));
        atomicAdd(base + 2, bf16_up(ra.z & 0xFFFFu));
        atomicAdd(base + 3, bf16_up(ra.z >> 16));
        atomicAdd(base + 4, bf16_up(ra.w & 0xFFFFu));
    }
    if (tid < 256 && (unsigned)(tid + 512) < cnt) {
        float* base = &slice[(rb.x >> 5) * CPADF + (rb.x & 31u) * N_SYN];
        atomicAdd(base + 0, bf16_up(rb.y & 0xFFFFu));
        atomicAdd(base + 1, bf16_up(rb.y >> 16));
        atomicAdd(base + 2, bf16_up(rb.z & 0xFFFFu));
        atomicAdd(base + 3, bf16_up(rb.z >> 16));
        atomicAdd(base + 4, bf16_up(rb.w & 0xFFFFu));
    }
    __syncthreads();

    // ---- convert once to bf16, transposed [c][k], (c&15)-swizzled ----
    // 2560 units = 160 c x 16 k-groups; reg-staged across the barrier.
    bf16x8 hi[5];
    unsigned bo[5];
#pragma unroll
    for (int j = 0; j < 5; ++j) {
        int m  = tid + j * 512;                  // 0..2559
        int c  = m % BCOLS;
        int kb = m / BCOLS;                      // 0..15
#pragma unroll
        for (int i = 0; i < 8; ++i) {
            int k = kb * 8 + i;
            float v = (k < N_BKG) ? slice[k * CPADF + c] : 0.f;
            hi[j][i] = (short)bf16_rne(v);
        }
        bo[j] = (unsigned)(((c << 8) + (kb << 4)) ^ ((c & 15) << 4));
    }
    __syncthreads();
#pragma unroll
    for (int j = 0; j < 5; ++j)
        *(bf16x8*)(lds + bo[j]) = hi[j];
    __syncthreads();

    // ---- MFMA GEMM with interleaved stores ----
    const int l  = tid & 63;
    const int wv = tid >> 6;                     // 0..7
    const int cg = wv & 1;                       // c-group (80 cols)
    const int tg = wv >> 1;                      // t-group (64 rows)
    const int lc = l & 15;
    const int lq = l >> 4;
    const size_t cb = (size_t)bin * BCOLS + cg * 80;

#pragma unroll
    for (int np = 0; np < 2; ++np) {             // t-tile pairs
        f32x4 acc[5][2];
#pragma unroll
        for (int m = 0; m < 5; ++m)
#pragma unroll
            for (int j = 0; j < 2; ++j)
                acc[m][j] = (f32x4){0.f, 0.f, 0.f, 0.f};

#pragma unroll
        for (int kk = 0; kk < 4; ++kk) {
            bf16x8 bs[2];
#pragma unroll
            for (int j = 0; j < 2; ++j) {
                int nt = tg * 4 + np * 2 + j;
                bs[j] = spbf[(nt * 4 + kk) * 64 + l];
            }
#pragma unroll
            for (int m = 0; m < 5; ++m) {
                int c = cg * 80 + m * 16 + lc;
                int bor = (((c << 8) + (kk << 6) + (lq << 4)) ^ ((c & 15) << 4));
                bf16x8 ah = *(const bf16x8*)(lds + bor);
#pragma unroll
                for (int j = 0; j < 2; ++j)
                    acc[m][j] = __builtin_amdgcn_mfma_f32_16x16x32_bf16(
                                    ah, bs[j], acc[m][j], 0, 0, 0);
            }
        }
        // store this t-tile pair now (spreads the write stream)
#pragma unroll
        for (int j = 0; j < 2; ++j) {
            int t = tg * 64 + (np * 2 + j) * 16 + lc;
            if (t < SEQ_T) {
#pragma unroll
                for (int m = 0; m < 5; ++m) {
                    size_t c = cb + m * 16 + lq * 4;
                    if (c < NCOL)
                        *(f32x4*)(out + (size_t)t * NCOL + c) = acc[m][j];
                }
            }
        }
    }
}

extern "C" void kernel_launch(void* const* d_in, const int* in_sizes, int n_in,
                              void* d_out, int out_size, void* d_ws, size_t ws_size,
                              hipStream_t stream) {
    const float* weights = (const float*)d_in[0];
    const float* tau     = (const float*)d_in[1];
    const float* spikes  = (const float*)d_in[2];
    const int*   rows    = (const int*)d_in[3];
    const int*   cols    = (const int*)d_in[4];
    float* out = (float*)d_out;

    char* ws = (char*)d_ws;
    unsigned* count = (unsigned*)(ws + WS_COUNT_OFF);
    bf16x8*   spbf  = (bf16x8*)(ws + WS_SPB_OFF);
    uint4*    rec   = (uint4*)(ws + WS_REC_OFF);

    hipMemsetAsync(count, 0, NBINS * sizeof(unsigned), stream);

    int eblocks = (N_EDGES + 255) / 256;
    bucket_kernel<<<eblocks, 256, 0, stream>>>(weights, tau, rows, cols, spikes,
                                               count, rec, spbf);

    fused_kernel<<<NBINS, 512, 0, stream>>>(count, rec, spbf, out);
}

// Round 10
// 119.583 us; speedup vs baseline: 1.3525x; 1.3525x over previous
//
#include <hip/hip_runtime.h>

// BackgroundNoiseLayer, round 10: round-6 core + XCD-partitioned records +
// interleaved stores.
//   out[t, n*5+r] = sum_k spikes[t,k] * W[k, n*5+r],
//   W[k, c] = scatter-add over edges e (cols[e]=k, rows[e]=n) of weights[e]*tau[e,r]
//
// memset: zero bin counters [bin][part]
// K1 : bucket edges (bin = row/16); record = 16 B {key, 5 bf16 w*tau} written
//      to partition part = blockIdx&7 of rec[bin][part][64]. With round-robin
//      block->XCD dispatch, each record cache line is written by ONE XCD ->
//      full-line L2 writebacks (fixes the partial-line RMW that made K1 ~28us).
//      Also builds the fragment-ordered bf16 spike table spbf[nt][kk][lane].
// K2 : per block (16 neurons = 80 cols): preload 8-partition records + 16
//      spike frags -> zero f32 LDS slice -> LDS atomic scatter -> one bf16
//      convert into transposed XOR-swizzled LDS (union, 32 KB total) -> MFMA
//      GEMM looped m-outer with stores interleaved per m-tile. Bijective XCD
//      swizzle on bin ids.

#define N_NEURONS 50000
#define N_BKG     100
#define N_SYN     5
#define N_EDGES   500000
#define SEQ_T     250
#define NCOL      (N_NEURONS * N_SYN)   // 250000
#define RPB       16                    // neurons per bin
#define NBINS     (N_NEURONS / RPB)     // 3125
#define NPART     8                     // record partitions (one per XCD)
#define CAP_P     64                    // records per (bin, part): mean 20, +9.8 sigma
#define RECS_BIN  (NPART * CAP_P)       // 512 records = 8 KB contiguous per bin
#define KPAD      128                   // K padded 100 -> 128
#define CPADF     80                    // f32 slice leading dim
#define BCOLS     80                    // output cols per bin
#define NXCD      8

#define LDS_BYTES 32000                 // f32 slice 100*80*4; bf16 area 20480 (union)

// d_ws layout
#define WS_COUNT_OFF 0                  // NBINS*NPART u32 = 100 KB
#define WS_SPB_OFF   131072             // 4096 * 16 B = 64 KB spike frags
#define WS_REC_OFF   262144             // NBINS*512*16 B = 25.6 MB

typedef __attribute__((ext_vector_type(8))) short bf16x8;
typedef __attribute__((ext_vector_type(4))) float f32x4;

__device__ inline unsigned short bf16_rne(float f) {
    unsigned u = __builtin_bit_cast(unsigned, f);
    u += 0x7FFFu + ((u >> 16) & 1u);
    return (unsigned short)(u >> 16);
}
__device__ inline float bf16_up(unsigned hw) {
    return __builtin_bit_cast(float, hw << 16);
}

// K1: bucket-append edges into XCD-local partition; gids < 4096 also build
// the fragment-ordered spike table: unit gid = (nt*4 + kk)*64 + lane,
// value[i] = bf16(spikes[t, k0+i]), t = nt*16+(lane&15), k0 = kk*32+(lane>>4)*8.
__global__ __launch_bounds__(256) void bucket_kernel(
        const float* __restrict__ weights,
        const float* __restrict__ tau,
        const int*   __restrict__ rows,
        const int*   __restrict__ cols,
        const float* __restrict__ spikes,
        unsigned* __restrict__ count,
        uint4* __restrict__ rec,
        bf16x8* __restrict__ spbf) {
    int gid = blockIdx.x * 256 + threadIdx.x;
    if (gid < 4096) {
        int lane = gid & 63;
        int kk   = (gid >> 6) & 3;
        int nt   = gid >> 8;
        int t    = nt * 16 + (lane & 15);
        int k0   = kk * 32 + (lane >> 4) * 8;
        bf16x8 v;
#pragma unroll
        for (int i = 0; i < 8; ++i) {
            float s = 0.f;
            if (t < SEQ_T && (k0 + i) < N_BKG)
                s = spikes[t * N_BKG + k0 + i];      // 0/1 -> bf16 exact
            v[i] = (short)bf16_rne(s);
        }
        spbf[gid] = v;
    }
    if (gid >= N_EDGES) return;
    int row = rows[gid];
    int col = cols[gid];
    float w = weights[gid];
    const float* tp = tau + (size_t)gid * N_SYN;
    int bin  = row >> 4;                         // row / RPB
    int part = blockIdx.x & (NPART - 1);         // XCD-local partition
    unsigned slot = atomicAdd(&count[bin * NPART + part], 1u);
    if (slot >= CAP_P) return;                   // statistically impossible
    uint4 r;
    r.x = ((unsigned)col << 4) | (unsigned)(row & 15);
    r.y = (unsigned)bf16_rne(w * tp[0]) | ((unsigned)bf16_rne(w * tp[1]) << 16);
    r.z = (unsigned)bf16_rne(w * tp[2]) | ((unsigned)bf16_rne(w * tp[3]) << 16);
    r.w = (unsigned)bf16_rne(w * tp[4]);
    rec[(size_t)bin * RECS_BIN + part * CAP_P + slot] = r;
}

// K2: fused scatter + convert + MFMA GEMM. 3125 blocks x 256 (4 waves).
// Block: neurons [16b,16b+16) -> output cols [80b, 80b+80).
// Swapped operands: A = W bf16 frag (M = c), B = spike frag (N = t),
// k = (l>>4)*8+i. D: col = t = l&15, row = c = (l>>4)*4+reg -> f32x4
// stores along c (mapping verified rounds 5-9).
__global__ __launch_bounds__(256, 4) void fused_kernel(
        const unsigned* __restrict__ count,
        const uint4* __restrict__ rec,
        const bf16x8* __restrict__ spbf,
        float* __restrict__ out) {
    __shared__ __align__(16) char lds[LDS_BYTES];
    float* slice = (float*)lds;                  // f32 [100][80]

    const int tid = threadIdx.x;
    const int l   = tid & 63;
    const int wv  = tid >> 6;
    const int lc  = l & 15;
    const int lq  = l >> 4;

    // bijective XCD swizzle: contiguous bin chunk per XCD (q=390, r=5)
    const int orig = blockIdx.x;
    const int xcd  = orig & (NXCD - 1);
    const int q    = NBINS >> 3;                 // 390
    const int r8   = NBINS & 7;                  // 5
    const int bin  = (xcd < r8 ? xcd * (q + 1)
                               : r8 * (q + 1) + (xcd - r8) * q) + (orig >> 3);

    // ---- preload records: wave wv owns partitions wv and wv+4 ----
    const uint4* rbin = rec + (size_t)bin * RECS_BIN;
    unsigned cntA = count[bin * NPART + wv];
    unsigned cntB = count[bin * NPART + 4 + wv];
    if (cntA > CAP_P) cntA = CAP_P;
    if (cntB > CAP_P) cntB = CAP_P;
    uint4 ra = rbin[wv * CAP_P + l];             // unguarded: region fully allocated
    uint4 rb = rbin[(4 + wv) * CAP_P + l];
    bool havea = (unsigned)l < cntA;
    bool haveb = (unsigned)l < cntB;

    // ---- preload all 16 spike fragments (held through the phases) ----
    bf16x8 bs[4][4];
#pragma unroll
    for (int n = 0; n < 4; ++n)
#pragma unroll
        for (int kk = 0; kk < 4; ++kk)
            bs[n][kk] = spbf[((wv * 4 + n) * 4 + kk) * 64 + l];

    // ---- zero f32 slice (8000 f32 = 2000 f32x4) ----
    {
        f32x4* s4 = (f32x4*)lds;
        f32x4 z = (f32x4){0.f, 0.f, 0.f, 0.f};
#pragma unroll
        for (int j = 0; j < 8; ++j) {
            int i = tid + j * 256;
            if (i < 2000) s4[i] = z;
        }
    }
    __syncthreads();

    // ---- LDS f32 atomic scatter ----
    if (havea) {
        float* base = &slice[(ra.x >> 4) * CPADF + (ra.x & 15u) * N_SYN];
        atomicAdd(base + 0, bf16_up(ra.y & 0xFFFFu));
        atomicAdd(base + 1, bf16_up(ra.y >> 16));
        atomicAdd(base + 2, bf16_up(ra.z & 0xFFFFu));
        atomicAdd(base + 3, bf16_up(ra.z >> 16));
        atomicAdd(base + 4, bf16_up(ra.w & 0xFFFFu));
    }
    if (haveb) {
        float* base = &slice[(rb.x >> 4) * CPADF + (rb.x & 15u) * N_SYN];
        atomicAdd(base + 0, bf16_up(rb.y & 0xFFFFu));
        atomicAdd(base + 1, bf16_up(rb.y >> 16));
        atomicAdd(base + 2, bf16_up(rb.z & 0xFFFFu));
        atomicAdd(base + 3, bf16_up(rb.z >> 16));
        atomicAdd(base + 4, bf16_up(rb.w & 0xFFFFu));
    }
    __syncthreads();

    // ---- convert once to bf16, transposed [c][k], XOR-swizzled ----
    // 1280 units of (c, 8 consecutive k); reg-staged across the barrier.
    bf16x8 hi[5];
    unsigned bo[5];
#pragma unroll
    for (int j = 0; j < 5; ++j) {
        int m  = tid + j * 256;                  // 0..1279
        int c  = m % BCOLS;
        int kb = m / BCOLS;                      // 0..15
#pragma unroll
        for (int i = 0; i < 8; ++i) {
            int k = kb * 8 + i;
            float v = (k < N_BKG) ? slice[k * CPADF + c] : 0.f;
            hi[j][i] = (short)bf16_rne(v);
        }
        bo[j] = (unsigned)(((c << 8) + (kb << 4)) ^ ((c & 7) << 4));
    }
    __syncthreads();
#pragma unroll
    for (int j = 0; j < 5; ++j)
        *(bf16x8*)(lds + bo[j]) = hi[j];
    __syncthreads();

    // ---- MFMA GEMM, m-outer with interleaved stores ----
    const size_t cb = (size_t)bin * BCOLS;
#pragma unroll
    for (int m = 0; m < 5; ++m) {
        f32x4 acc[4];
#pragma unroll
        for (int n = 0; n < 4; ++n)
            acc[n] = (f32x4){0.f, 0.f, 0.f, 0.f};

        int c = m * 16 + lc;
#pragma unroll
        for (int kk = 0; kk < 4; ++kk) {
            int bor = (((c << 8) + (kk << 6) + (lq << 4)) ^ ((c & 7) << 4));
            bf16x8 ah = *(const bf16x8*)(lds + bor);
#pragma unroll
            for (int n = 0; n < 4; ++n)
                acc[n] = __builtin_amdgcn_mfma_f32_16x16x32_bf16(
                             ah, bs[n][kk], acc[n], 0, 0, 0);
        }
        // store this m-tile now (spreads the write stream across the GEMM)
        size_t cs = cb + m * 16 + lq * 4;
#pragma unroll
        for (int n = 0; n < 4; ++n) {
            int t = (wv * 4 + n) * 16 + lc;
            if (t < SEQ_T)
                *(f32x4*)(out + (size_t)t * NCOL + cs) = acc[n];
        }
    }
}

extern "C" void kernel_launch(void* const* d_in, const int* in_sizes, int n_in,
                              void* d_out, int out_size, void* d_ws, size_t ws_size,
                              hipStream_t stream) {
    const float* weights = (const float*)d_in[0];
    const float* tau     = (const float*)d_in[1];
    const float* spikes  = (const float*)d_in[2];
    const int*   rows    = (const int*)d_in[3];
    const int*   cols    = (const int*)d_in[4];
    float* out = (float*)d_out;

    char* ws = (char*)d_ws;
    unsigned* count = (unsigned*)(ws + WS_COUNT_OFF);
    bf16x8*   spbf  = (bf16x8*)(ws + WS_SPB_OFF);
    uint4*    rec   = (uint4*)(ws + WS_REC_OFF);

    hipMemsetAsync(count, 0, NBINS * NPART * sizeof(unsigned), stream);

    int eblocks = (N_EDGES + 255) / 256;
    bucket_kernel<<<eblocks, 256, 0, stream>>>(weights, tau, rows, cols, spikes,
                                               count, rec, spbf);

    fused_kernel<<<NBINS, 256, 0, stream>>>(count, rec, spbf, out);
}

// Round 11
// 112.563 us; speedup vs baseline: 1.4368x; 1.0624x over previous
//
#include <hip/hip_runtime.h>

// BackgroundNoiseLayer, round 11: round-10 core + three mechanism fixes:
//  (a) count[part][bin] layout (counter lines XCD-private, no L2 ping-pong)
//  (b) bs preload moved after convert (peak VGPR ~90 < 128, no spill)
//  (c) within-XCD-chunk strided bin traversal (j*37 mod q): concurrent blocks
//      cover ~all 4KB pages of the 1MB out-row -> full HBM channel coverage
//      (out rows are 1MB apart; a block's 250 segments share all low address
//      bits, so channel diversity comes only from concurrent-bin diversity).
//
// memset: zero bin counters [part][bin]
// K1 : bucket edges (bin = row/16); 16 B record {key, 5 bf16 w*tau} into
//      partition part = blockIdx&7 (XCD-local lines); also builds the
//      fragment-ordered bf16 spike table spbf[nt][kk][lane].
// K2 : per block (16 neurons = 80 cols): preload records -> zero f32 LDS
//      slice -> LDS atomic scatter -> one bf16 convert into transposed
//      XOR-swizzled LDS (union) -> preload spike frags -> MFMA GEMM m-outer
//      with interleaved f32x4 stores.

#define N_NEURONS 50000
#define N_BKG     100
#define N_SYN     5
#define N_EDGES   500000
#define SEQ_T     250
#define NCOL      (N_NEURONS * N_SYN)   // 250000
#define RPB       16                    // neurons per bin
#define NBINS     (N_NEURONS / RPB)     // 3125
#define NPART     8                     // record partitions (one per XCD)
#define CAP_P     64                    // records per (bin, part): mean 20, +9.8 sigma
#define RECS_BIN  (NPART * CAP_P)       // 512 records = 8 KB contiguous per bin
#define CPADF     80                    // f32 slice leading dim
#define BCOLS     80                    // output cols per bin
#define STRIDE_J  37                    // coprime to 390 and 391

#define LDS_BYTES 32000                 // f32 slice 100*80*4; bf16 area 20480 (union)

// d_ws layout
#define WS_COUNT_OFF 0                  // NPART*NBINS u32 = 100 KB
#define WS_SPB_OFF   131072             // 4096 * 16 B = 64 KB spike frags
#define WS_REC_OFF   262144             // NBINS*512*16 B = 25.6 MB

typedef __attribute__((ext_vector_type(8))) short bf16x8;
typedef __attribute__((ext_vector_type(4))) float f32x4;

__device__ inline unsigned short bf16_rne(float f) {
    unsigned u = __builtin_bit_cast(unsigned, f);
    u += 0x7FFFu + ((u >> 16) & 1u);
    return (unsigned short)(u >> 16);
}
__device__ inline float bf16_up(unsigned hw) {
    return __builtin_bit_cast(float, hw << 16);
}

// K1: bucket-append edges into XCD-local partition; gids < 4096 also build
// the fragment-ordered spike table: unit gid = (nt*4 + kk)*64 + lane,
// value[i] = bf16(spikes[t, k0+i]), t = nt*16+(lane&15), k0 = kk*32+(lane>>4)*8.
__global__ __launch_bounds__(256) void bucket_kernel(
        const float* __restrict__ weights,
        const float* __restrict__ tau,
        const int*   __restrict__ rows,
        const int*   __restrict__ cols,
        const float* __restrict__ spikes,
        unsigned* __restrict__ count,
        uint4* __restrict__ rec,
        bf16x8* __restrict__ spbf) {
    int gid = blockIdx.x * 256 + threadIdx.x;
    if (gid < 4096) {
        int lane = gid & 63;
        int kk   = (gid >> 6) & 3;
        int nt   = gid >> 8;
        int t    = nt * 16 + (lane & 15);
        int k0   = kk * 32 + (lane >> 4) * 8;
        bf16x8 v;
#pragma unroll
        for (int i = 0; i < 8; ++i) {
            float s = 0.f;
            if (t < SEQ_T && (k0 + i) < N_BKG)
                s = spikes[t * N_BKG + k0 + i];      // 0/1 -> bf16 exact
            v[i] = (short)bf16_rne(s);
        }
        spbf[gid] = v;
    }
    if (gid >= N_EDGES) return;
    int row = rows[gid];
    int col = cols[gid];
    float w = weights[gid];
    const float* tp = tau + (size_t)gid * N_SYN;
    int bin  = row >> 4;                         // row / RPB
    int part = blockIdx.x & (NPART - 1);         // XCD-local partition
    // count[part][bin]: each partition's counters contiguous -> lines stay
    // in one XCD's L2 (partitions map to XCDs under round-robin dispatch)
    unsigned slot = atomicAdd(&count[part * NBINS + bin], 1u);
    if (slot >= CAP_P) return;                   // statistically impossible
    uint4 r;
    r.x = ((unsigned)col << 4) | (unsigned)(row & 15);
    r.y = (unsigned)bf16_rne(w * tp[0]) | ((unsigned)bf16_rne(w * tp[1]) << 16);
    r.z = (unsigned)bf16_rne(w * tp[2]) | ((unsigned)bf16_rne(w * tp[3]) << 16);
    r.w = (unsigned)bf16_rne(w * tp[4]);
    rec[(size_t)bin * RECS_BIN + part * CAP_P + slot] = r;
}

// K2: fused scatter + convert + MFMA GEMM. 3125 blocks x 256 (4 waves).
// Block: neurons [16b,16b+16) -> output cols [80b, 80b+80).
// Swapped operands: A = W bf16 frag (M = c), B = spike frag (N = t),
// k = (l>>4)*8+i. D: col = t = l&15, row = c = (l>>4)*4+reg -> f32x4
// stores along c (mapping verified rounds 5-10).
__global__ __launch_bounds__(256, 4) void fused_kernel(
        const unsigned* __restrict__ count,
        const uint4* __restrict__ rec,
        const bf16x8* __restrict__ spbf,
        float* __restrict__ out) {
    __shared__ __align__(16) char lds[LDS_BYTES];
    float* slice = (float*)lds;                  // f32 [100][80]

    const int tid = threadIdx.x;
    const int l   = tid & 63;
    const int wv  = tid >> 6;
    const int lc  = l & 15;
    const int lq  = l >> 4;

    // XCD chunking (L2 locality for split out-lines) + strided traversal
    // within the chunk (channel coverage): bijective overall.
    const int orig = blockIdx.x;
    const int xcd  = orig & 7;
    const int j    = orig >> 3;
    const int qx   = (xcd < 5) ? 391 : 390;      // 3125 = 5*391 + 3*390
    const int base = (xcd < 5) ? xcd * 391 : 5 * 391 + (xcd - 5) * 390;
    const int bin  = base + (j * STRIDE_J) % qx;

    // ---- preload records: wave wv owns partitions wv and wv+4 ----
    const uint4* rbin = rec + (size_t)bin * RECS_BIN;
    unsigned cntA = count[wv * NBINS + bin];
    unsigned cntB = count[(4 + wv) * NBINS + bin];
    if (cntA > CAP_P) cntA = CAP_P;
    if (cntB > CAP_P) cntB = CAP_P;
    uint4 ra = rbin[wv * CAP_P + l];             // unguarded: region fully allocated
    uint4 rb = rbin[(4 + wv) * CAP_P + l];
    bool havea = (unsigned)l < cntA;
    bool haveb = (unsigned)l < cntB;

    // ---- zero f32 slice (8000 f32 = 2000 f32x4) ----
    {
        f32x4* s4 = (f32x4*)lds;
        f32x4 z = (f32x4){0.f, 0.f, 0.f, 0.f};
#pragma unroll
        for (int jj = 0; jj < 8; ++jj) {
            int i = tid + jj * 256;
            if (i < 2000) s4[i] = z;
        }
    }
    __syncthreads();

    // ---- LDS f32 atomic scatter ----
    if (havea) {
        float* bp = &slice[(ra.x >> 4) * CPADF + (ra.x & 15u) * N_SYN];
        atomicAdd(bp + 0, bf16_up(ra.y & 0xFFFFu));
        atomicAdd(bp + 1, bf16_up(ra.y >> 16));
        atomicAdd(bp + 2, bf16_up(ra.z & 0xFFFFu));
        atomicAdd(bp + 3, bf16_up(ra.z >> 16));
        atomicAdd(bp + 4, bf16_up(ra.w & 0xFFFFu));
    }
    if (haveb) {
        float* bp = &slice[(rb.x >> 4) * CPADF + (rb.x & 15u) * N_SYN];
        atomicAdd(bp + 0, bf16_up(rb.y & 0xFFFFu));
        atomicAdd(bp + 1, bf16_up(rb.y >> 16));
        atomicAdd(bp + 2, bf16_up(rb.z & 0xFFFFu));
        atomicAdd(bp + 3, bf16_up(rb.z >> 16));
        atomicAdd(bp + 4, bf16_up(rb.w & 0xFFFFu));
    }
    __syncthreads();

    // ---- convert once to bf16, transposed [c][k], XOR-swizzled ----
    // 1280 units of (c, 8 consecutive k); reg-staged across the barrier.
    bf16x8 hi[5];
#pragma unroll
    for (int jj = 0; jj < 5; ++jj) {
        int m  = tid + jj * 256;                 // 0..1279
        int c  = m % BCOLS;
        int kb = m / BCOLS;                      // 0..15
#pragma unroll
        for (int i = 0; i < 8; ++i) {
            int k = kb * 8 + i;
            float v = (k < N_BKG) ? slice[k * CPADF + c] : 0.f;
            hi[jj][i] = (short)bf16_rne(v);
        }
    }
    __syncthreads();
#pragma unroll
    for (int jj = 0; jj < 5; ++jj) {
        int m  = tid + jj * 256;
        int c  = m % BCOLS;
        int kb = m / BCOLS;
        unsigned bo = (unsigned)(((c << 8) + (kb << 4)) ^ ((c & 7) << 4));
        *(bf16x8*)(lds + bo) = hi[jj];
    }

    // ---- preload spike fragments AFTER convert regs die (peak VGPR ~90) ----
    bf16x8 bs[4][4];
#pragma unroll
    for (int n = 0; n < 4; ++n)
#pragma unroll
        for (int kk = 0; kk < 4; ++kk)
            bs[n][kk] = spbf[((wv * 4 + n) * 4 + kk) * 64 + l];
    __syncthreads();

    // ---- MFMA GEMM, m-outer with interleaved stores ----
    const size_t cb = (size_t)bin * BCOLS;
#pragma unroll
    for (int m = 0; m < 5; ++m) {
        f32x4 acc[4];
#pragma unroll
        for (int n = 0; n < 4; ++n)
            acc[n] = (f32x4){0.f, 0.f, 0.f, 0.f};

        int c = m * 16 + lc;
#pragma unroll
        for (int kk = 0; kk < 4; ++kk) {
            int bor = (((c << 8) + (kk << 6) + (lq << 4)) ^ ((c & 7) << 4));
            bf16x8 ah = *(const bf16x8*)(lds + bor);
#pragma unroll
            for (int n = 0; n < 4; ++n)
                acc[n] = __builtin_amdgcn_mfma_f32_16x16x32_bf16(
                             ah, bs[n][kk], acc[n], 0, 0, 0);
        }
        // store this m-tile now (spreads the write stream across the GEMM)
        size_t cs = cb + m * 16 + lq * 4;
#pragma unroll
        for (int n = 0; n < 4; ++n) {
            int t = (wv * 4 + n) * 16 + lc;
            if (t < SEQ_T)
                *(f32x4*)(out + (size_t)t * NCOL + cs) = acc[n];
        }
    }
}

extern "C" void kernel_launch(void* const* d_in, const int* in_sizes, int n_in,
                              void* d_out, int out_size, void* d_ws, size_t ws_size,
                              hipStream_t stream) {
    const float* weights = (const float*)d_in[0];
    const float* tau     = (const float*)d_in[1];
    const float* spikes  = (const float*)d_in[2];
    const int*   rows    = (const int*)d_in[3];
    const int*   cols    = (const int*)d_in[4];
    float* out = (float*)d_out;

    char* ws = (char*)d_ws;
    unsigned* count = (unsigned*)(ws + WS_COUNT_OFF);
    bf16x8*   spbf  = (bf16x8*)(ws + WS_SPB_OFF);
    uint4*    rec   = (uint4*)(ws + WS_REC_OFF);

    hipMemsetAsync(count, 0, NPART * NBINS * sizeof(unsigned), stream);

    int eblocks = (N_EDGES + 255) / 256;
    bucket_kernel<<<eblocks, 256, 0, stream>>>(weights, tau, rows, cols, spikes,
                                               count, rec, spbf);

    fused_kernel<<<NBINS, 256, 0, stream>>>(count, rec, spbf, out);
}